// Round 1
// baseline (85.347 us; speedup 1.0000x reference)
//
#include <hip/hip_runtime.h>

#define RR 4
#define LRN 256
#define HRN 1024
#define SCALE (255.0f/1023.0f)

typedef float v2 __attribute__((ext_vector_type(2)));

// ---- workspace layout ----
// [0,4K)      : int   lutA[1024]            per-coord anchor
// [4K,52K)    : float4 lutW[1024][3]        per-coord weights (minus, plus, full)
// [64K, ...)  : v2    AB[3][256][256]       guided-filter (A,b) plane
#define WS_LUTW 4096
#define WS_AB   65536

// Anchor: lr index of the lowest tap of any pattern at out-coord u.
__device__ inline int anchor_of(int u) {
    int k = min(max(u - 4, 0), HRN - 1);
    float t = (float)k * SCALE;
    int i = (int)t; if (i > LRN - 2) i = LRN - 2;
    return i;
}

// Accumulated 4-tap lr weights for hr taps k0..k1 (clamped), relative to anchor a.
__device__ inline float4 mkw(int k0, int k1, int a) {
    float4 w = make_float4(0.f, 0.f, 0.f, 0.f);
    for (int k = k0; k <= k1; ++k) {
        int kc = min(max(k, 0), HRN - 1);
        float t = (float)kc * SCALE;
        int i = (int)t; if (i > LRN - 2) i = LRN - 2;
        float f = t - (float)i;
        int off = i - a;                 // in [0,2]
        float wa = 1.0f - f, wb = f;
        w.x += (off == 0) ? wa : 0.0f;
        w.y += (off == 1) ? wa : ((off == 0) ? wb : 0.0f);
        w.z += (off == 2) ? wa : ((off == 1) ? wb : 0.0f);
        w.w += (off == 2) ? wb : 0.0f;
    }
    return w;
}

// ============================================================================
// Kernel 1: compute LUT (1024 entries) + guided-filter (A,b) plane at LR.
// Tile: 32 cols x 16 rows of lr cells per block; grid (8,16,3).
// Accumulation order matches the previous fused kernel exactly (bit-identical).
// ============================================================================
__global__ __launch_bounds__(256, 4) void lr_kernel(
    const float* __restrict__ lrx, const float* __restrict__ lry,
    float* __restrict__ ws)
{
    __shared__ float4 sV[24][40];    // staged stats (x,y,xy,xx), rows Y0-4..Y0+19, cols X0-4..X0+35
    __shared__ float4 sHS[24][32];   // horizontal 9-tap sums

    const int c  = blockIdx.z;
    const int X0 = blockIdx.x * 32, Y0 = blockIdx.y * 16;
    const int tid = threadIdx.y * 32 + threadIdx.x;
    const float* px = lrx + c * LRN * LRN;
    const float* py = lry + c * LRN * LRN;

    // one-off: weight LUT (8 blocks x 128 threads cover 1024 coords)
    if (c == 0 && blockIdx.y == 0 && tid < 128) {
        int u = blockIdx.x * 128 + tid;
        int a = anchor_of(u);
        ((int*)ws)[u] = a;
        float4* w = (float4*)((char*)ws + WS_LUTW) + u * 3;
        w[0] = mkw(u - 4, u,     a);   // minus side (L / T)
        w[1] = mkw(u,     u + 4, a);   // plus side  (R / B)
        w[2] = mkw(u - 4, u + 4, a);   // full       (F)
    }

    // stage lr stats, coords clamped (rep-pad)
    for (int i = tid; i < 24 * 40; i += 256) {
        int r = i / 40, cc = i - r * 40;
        int gy = min(max(Y0 - 4 + r, 0), LRN - 1);
        int gx = min(max(X0 - 4 + cc, 0), LRN - 1);
        float xv = px[gy * LRN + gx];
        float yv = py[gy * LRN + gx];
        sV[r][cc] = make_float4(xv, yv, xv * yv, xv * xv);
    }
    __syncthreads();

    // horizontal 9-tap sums
    for (int i = tid; i < 24 * 32; i += 256) {
        int r = i / 32, cc = i & 31;
        float4 s = sV[r][cc];
        #pragma unroll
        for (int k = 1; k < 9; ++k) {
            float4 v = sV[r][cc + k];
            s.x += v.x; s.y += v.y; s.z += v.z; s.w += v.w;
        }
        sHS[r][cc] = s;
    }
    __syncthreads();

    // vertical 9-tap + guided-filter finalize -> AB plane in ws
    v2* ab_out = (v2*)((char*)ws + WS_AB);
    for (int i = tid; i < 16 * 32; i += 256) {
        int r = i / 32, cc = i & 31;
        float4 s = sHS[r][cc];
        #pragma unroll
        for (int k = 1; k < 9; ++k) {
            float4 v = sHS[r + k][cc];
            s.x += v.x; s.y += v.y; s.z += v.z; s.w += v.w;
        }
        const float inv81 = 1.0f / 81.0f;
        float mx = s.x * inv81, my = s.y * inv81;
        float cov = s.z * inv81 - mx * my;
        float var = s.w * inv81 - mx * mx;
        float A = cov / (var + 2.0f);
        float B = my - A * mx;
        v2 ab; ab.x = A; ab.y = B;
        ab_out[(c * LRN + (Y0 + r)) * LRN + X0 + cc] = ab;
    }
}

// ============================================================================
// Kernel 2: upsample + 8-direction side-window stencil.
// Tile: 32 cols x 32 rows of HR pixels, block (32,8), 4 rows/thread.
// ============================================================================
#define TX 32
#define TYR 32
#define BTH 8
#define NROW (TYR / BTH)   // 4
#define LRC 12             // lr cols of AB needed (span of 32 hr cols + taps)
#define LRR 12             // lr rows of AB needed (span of 32 hr rows + taps)

__global__ __launch_bounds__(256, 7) void hr_kernel(
    const float* __restrict__ hrx, const float* __restrict__ ws,
    float* __restrict__ out)
{
    __shared__ float4 sTB[TYR][LRC];    // packed (T.x,T.y,B.x,B.y) vertical mixes
    __shared__ v2     sF[TYR][LRC];     // full vertical mix
    __shared__ v2     sAB[LRR][LRC];    // lr (A,b) patch
    __shared__ float4 sYW[TYR][3];      // per-row weights: T,B,F
    __shared__ int    sYA[TYR];
    __shared__ float4 sXW[TX][3];       // per-col weights: L,R,F
    __shared__ int    sXA[TX];

    const int c  = blockIdx.z;
    const int X0 = blockIdx.x * TX, Y0 = blockIdx.y * TYR;
    const int tid = threadIdx.y * TX + threadIdx.x;

    const int*    lutA = (const int*)ws;
    const float4* lutW = (const float4*)((const char*)ws + WS_LUTW);
    const v2*     AB   = (const v2*)((const char*)ws + WS_AB) + c * LRN * LRN;

    const int rowbase = lutA[Y0];       // uniform -> scalar load
    const int colbase = lutA[X0];

    // phase 0: load LUT slices + AB patch (disjoint thread ranges, 1 barrier)
    if (tid < TX) {
        int u = X0 + tid;
        sXA[tid] = lutA[u] - colbase;
        sXW[tid][0] = lutW[u * 3 + 0];
        sXW[tid][1] = lutW[u * 3 + 1];
        sXW[tid][2] = lutW[u * 3 + 2];
    } else if (tid >= 64 && tid < 64 + TYR) {
        int r = tid - 64, u = Y0 + r;
        sYA[r] = lutA[u] - rowbase;
        sYW[r][0] = lutW[u * 3 + 0];
        sYW[r][1] = lutW[u * 3 + 1];
        sYW[r][2] = lutW[u * 3 + 2];
    } else if (tid >= 96 && tid < 96 + LRR * LRC) {
        int i = tid - 96;
        int r = i / LRC, cc = i - r * LRC;
        int gy = min(rowbase + r, LRN - 1);
        int gx = min(colbase + cc, LRN - 1);
        sAB[r][cc] = AB[gy * LRN + gx];
    }
    __syncthreads();

    // phase D: vertical 4-tap mixes, TYR rows x LRC lr cols
    for (int i = tid; i < TYR * LRC; i += 256) {
        int r = i / LRC, cc = i - r * LRC;
        int ra = sYA[r];
        float4 wT = sYW[r][0], wB = sYW[r][1], wF = sYW[r][2];
        v2 v0 = sAB[ra][cc],     v1 = sAB[ra + 1][cc];
        v2 v2_ = sAB[ra + 2][cc], v3 = sAB[ra + 3][cc];
        v2 t, b, f;
        t = v0 * wT.x; t = __builtin_elementwise_fma((v2)(wT.y), v1, t);
        t = __builtin_elementwise_fma((v2)(wT.z), v2_, t);
        t = __builtin_elementwise_fma((v2)(wT.w), v3, t);
        b = v0 * wB.x; b = __builtin_elementwise_fma((v2)(wB.y), v1, b);
        b = __builtin_elementwise_fma((v2)(wB.z), v2_, b);
        b = __builtin_elementwise_fma((v2)(wB.w), v3, b);
        f = v0 * wF.x; f = __builtin_elementwise_fma((v2)(wF.y), v1, f);
        f = __builtin_elementwise_fma((v2)(wF.z), v2_, f);
        f = __builtin_elementwise_fma((v2)(wF.w), v3, f);
        sTB[r][cc] = make_float4(t.x, t.y, b.x, b.y);
        sF[r][cc]  = f;
    }
    __syncthreads();

    // phase E: per-pixel horizontal combine + argmin
    const int tx = threadIdx.x, tyw = threadIdx.y;
    const int c0 = sXA[tx];
    const float4 wL = sXW[tx][0], wR = sXW[tx][1], wFh = sXW[tx][2];
    const float i45 = 1.0f / 45.0f, i25 = 1.0f / 25.0f;
    const float* hp = hrx + (c * HRN + Y0 + tyw) * HRN + X0 + tx;
    float*       op = out + (c * HRN + Y0 + tyw) * HRN + X0 + tx;

    #pragma unroll
    for (int j = 0; j < NROW; ++j) {
        const int r = tyw + j * BTH;
        v2 aL = 0, aR = 0, aU = 0, aD = 0;
        v2 aNW = 0, aNE = 0, aSW = 0, aSE = 0;
        #pragma unroll
        for (int k = 0; k < 4; ++k) {
            float wl = (k==0)?wL.x:(k==1)?wL.y:(k==2)?wL.z:wL.w;
            float wr = (k==0)?wR.x:(k==1)?wR.y:(k==2)?wR.z:wR.w;
            float wf = (k==0)?wFh.x:(k==1)?wFh.y:(k==2)?wFh.z:wFh.w;
            float4 tb = sTB[r][c0 + k];
            v2 tv; tv.x = tb.x; tv.y = tb.y;
            v2 bv; bv.x = tb.z; bv.y = tb.w;
            v2 fv = sF[r][c0 + k];
            aL  = __builtin_elementwise_fma((v2)(wl), fv, aL);
            aR  = __builtin_elementwise_fma((v2)(wr), fv, aR);
            aU  = __builtin_elementwise_fma((v2)(wf), tv, aU);
            aD  = __builtin_elementwise_fma((v2)(wf), bv, aD);
            aNW = __builtin_elementwise_fma((v2)(wl), tv, aNW);
            aNE = __builtin_elementwise_fma((v2)(wr), tv, aNE);
            aSW = __builtin_elementwise_fma((v2)(wl), bv, aSW);
            aSE = __builtin_elementwise_fma((v2)(wr), bv, aSE);
        }
        float xv = hp[j * BTH * HRN];

        float d0 = fmaf(i45, fmaf(aL.x,  xv, aL.y),  -xv); // L
        float d1 = fmaf(i45, fmaf(aR.x,  xv, aR.y),  -xv); // R
        float d2 = fmaf(i45, fmaf(aU.x,  xv, aU.y),  -xv); // U
        float d3 = fmaf(i45, fmaf(aD.x,  xv, aD.y),  -xv); // D
        float d4 = fmaf(i25, fmaf(aNW.x, xv, aNW.y), -xv); // NW
        float d5 = fmaf(i25, fmaf(aNE.x, xv, aNE.y), -xv); // NE
        float d6 = fmaf(i25, fmaf(aSW.x, xv, aSW.y), -xv); // SW
        float d7 = fmaf(i25, fmaf(aSE.x, xv, aSE.y), -xv); // SE

        float a0 = fabsf(d0), a1 = fabsf(d1), a2 = fabsf(d2), a3 = fabsf(d3);
        float a4 = fabsf(d4), a5 = fabsf(d5), a6 = fabsf(d6), a7 = fabsf(d7);
        bool c01 = a0 <= a1; float w01 = c01 ? d0 : d1; float m01 = c01 ? a0 : a1;
        bool c23 = a2 <= a3; float w23 = c23 ? d2 : d3; float m23 = c23 ? a2 : a3;
        bool c45 = a4 <= a5; float w45 = c45 ? d4 : d5; float m45 = c45 ? a4 : a5;
        bool c67 = a6 <= a7; float w67 = c67 ? d6 : d7; float m67 = c67 ? a6 : a7;
        bool cA_ = m01 <= m23; float wA = cA_ ? w01 : w23; float mA = cA_ ? m01 : m23;
        bool cB_ = m45 <= m67; float wB_ = cB_ ? w45 : w67; float mB = cB_ ? m45 : m67;
        float bd = (mA <= mB) ? wA : wB_;

        float res = __builtin_amdgcn_fmed3f(truncf(bd + xv), 0.0f, 255.0f);
        op[j * BTH * HRN] = res;
    }
}

extern "C" void kernel_launch(void* const* d_in, const int* in_sizes, int n_in,
                              void* d_out, int out_size, void* d_ws, size_t ws_size,
                              hipStream_t stream) {
    const float* lrx = (const float*)d_in[0];
    const float* lry = (const float*)d_in[1];
    const float* hrx = (const float*)d_in[2];
    (void)d_in[3]; (void)in_sizes; (void)n_in; (void)out_size; (void)ws_size;

    float* ws   = (float*)d_ws;
    float* outp = (float*)d_out;

    lr_kernel<<<dim3(LRN / 32, LRN / 16, 3), dim3(32, 8), 0, stream>>>(lrx, lry, ws);
    hr_kernel<<<dim3(HRN / TX, HRN / TYR, 3), dim3(TX, BTH), 0, stream>>>(hrx, ws, outp);
}